// Round 9
// baseline (103.757 us; speedup 1.0000x reference)
//
#include <hip/hip_runtime.h>
#include <stdint.h>

#define NB 16384      // batch
#define NK 64         // neighbors per node
#define NF 128        // feature dim
#define NS 16         // samples per row
#define RPB 4         // rows (waves) per block

// ---------------------------------------------------------------------------
// Bit-exact replicas of XLA:CPU's float32 exp/log (Cephes-derived polynomials
// from llvm_ir_runtime.cc GenerateVF32Exp/GenerateVF32Log; fmuladd -> FMA).
// DO NOT TOUCH: verified absmax == 0 vs JAX reference in R1/R4/R6/R7/R8.
// ---------------------------------------------------------------------------
__device__ __forceinline__ float xla_exp_f32(float x_in) {
#pragma clang fp contract(off)
  const float exp_hi = 88.3762626647950f;
  const float exp_lo = -88.3762626647949f;
  const float log2ef = 1.44269504088896341f;
  const float c1 = 0.693359375f;
  const float c2 = -2.12194440e-4f;
  const float p0 = 1.9875691500E-4f;
  const float p1 = 1.3981999507E-3f;
  const float p2 = 8.3334519073E-3f;
  const float p3 = 4.1665795894E-2f;
  const float p4 = 1.6666665459E-1f;
  const float p5 = 5.0000001201E-1f;

  float x = fminf(fmaxf(x_in, exp_lo), exp_hi);
  float fx = floorf(fmaf(x, log2ef, 0.5f));
  float tmp = c1 * fx;
  float z2 = c2 * fx;
  x = x - tmp;
  x = x - z2;
  float z = x * x;
  float y = fmaf(x, p0, p1);
  y = fmaf(y, x, p2);
  y = fmaf(y, x, p3);
  y = fmaf(y, x, p4);
  y = fmaf(y, x, p5);
  y = fmaf(y, z, x);
  y = y + 1.0f;
  int n = (int)fx;
  float two_n = __int_as_float((n + 127) << 23);
  return fmaxf(y * two_n, x_in);
}

__device__ __forceinline__ float xla_log_f32(float x_in) {
#pragma clang fp contract(off)
  const float sqrthf = 0.707106781186547524f;
  const float p0 = 7.0376836292E-2f;
  const float p1 = -1.1514610310E-1f;
  const float p2 = 1.1676998740E-1f;
  const float p3 = -1.2420140846E-1f;
  const float p4 = 1.4249322787E-1f;
  const float p5 = -1.6668057665E-1f;
  const float p6 = 2.0000714765E-1f;
  const float p7 = -2.4999993993E-1f;
  const float p8 = 3.3333331174E-1f;
  const float q1 = -2.12194440e-4f;
  const float q2 = 0.693359375f;

  float t = fmaxf(x_in, __uint_as_float(0x00800000u));
  uint32_t bits = __float_as_uint(t);
  float e = (float)((int)(bits >> 23) - 0x7f) + 1.0f;
  float m = __uint_as_float((bits & 0x007fffffu) | 0x3f000000u);
  bool lt = (m < sqrthf);
  float madd = lt ? m : 0.0f;
  e = e - (lt ? 1.0f : 0.0f);
  m = (m + madd) - 1.0f;

  float z = m * m;
  float y = fmaf(m, p0, p1);
  y = fmaf(y, m, p2);
  y = fmaf(y, m, p3);
  y = fmaf(y, m, p4);
  y = fmaf(y, m, p5);
  y = fmaf(y, m, p6);
  y = fmaf(y, m, p7);
  y = fmaf(y, m, p8);
  y = y * m;
  y = y * z;
  y = fmaf(e, q1, y);
  y = y - 0.5f * z;
  float r = m + y;
  r = fmaf(e, q2, r);
  return r;
}

// ---------------------------------------------------------------------------
// Threefry-2x32 with key (0, 42) == jax.random.key(42).
// ---------------------------------------------------------------------------
__device__ __forceinline__ void threefry2x32_k42(uint32_t c0, uint32_t c1,
                                                 uint32_t& o0, uint32_t& o1) {
  const uint32_t k0 = 0u, k1 = 42u;
  const uint32_t k2 = k0 ^ k1 ^ 0x1BD11BDAu;
  uint32_t x0 = c0 + k0, x1 = c1 + k1;
#define TF_R(r) { x0 += x1; x1 = (x1 << (r)) | (x1 >> (32 - (r))); x1 ^= x0; }
  TF_R(13) TF_R(15) TF_R(26) TF_R(6)
  x0 += k1; x1 += k2 + 1u;
  TF_R(17) TF_R(29) TF_R(16) TF_R(24)
  x0 += k2; x1 += k0 + 2u;
  TF_R(13) TF_R(15) TF_R(26) TF_R(6)
  x0 += k0; x1 += k1 + 3u;
  TF_R(17) TF_R(29) TF_R(16) TF_R(24)
  x0 += k1; x1 += k2 + 4u;
  TF_R(13) TF_R(15) TF_R(26) TF_R(6)
  x0 += k2; x1 += k0 + 5u;
#undef TF_R
  o0 = x0; o1 = x1;
}

// jax partitionable threefry, 32-bit path: bits[m] = out0 ^ out1, m < 2^24.
__device__ __forceinline__ uint32_t jax_random_bits32(uint32_t m) {
  uint32_t a, b;
  threefry2x32_k42(0u, m, a, b);
  return a ^ b;
}

__device__ __forceinline__ float gumbel_from_bits(uint32_t bits) {
#pragma clang fp contract(off)
  const float tiny = 1.17549435e-38f;
  float f = __uint_as_float((bits >> 9) | 0x3f800000u) - 1.0f;
  float u = fmaxf(tiny, f + tiny);
  return -xla_log_f32(-xla_log_f32(u));
}

#define AS1 __attribute__((address_space(1)))
#define AS3 __attribute__((address_space(3)))

// ---------------------------------------------------------------------------
// R8 + pipelined staging. Row split into 8 chunks x 64 B, ping-ponged across
// two 4 KB halves of the per-wave 8 KB stage buffer. Each iteration issues
// chunk c+1 BEFORE waiting vmcnt(4) (= chunk c complete, c+1 in flight) --
// loads never drain to 0 inside the loop. Stage pointers precomputed once
// (zero per-chunk address VALU beyond 4 pointer bumps). XOR slot-swizzle on
// the GLOBAL source (m173) gives a conflict-minimal read layout. Consume
// order = global element order -> bit-exact. Math blocks verbatim R8.
// ---------------------------------------------------------------------------
__global__ void __launch_bounds__(256)
dns_kernel(const int* __restrict__ ids, const float* __restrict__ features,
           const int* __restrict__ adj, int* __restrict__ out) {
#pragma clang fp contract(off)
  __shared__ __align__(16) char sbuf[RPB][8192];   // stage buf, later zsh
  __shared__ __align__(16) float fc[RPB][NF];
  __shared__ __align__(16) float esh[RPB][NK];
  __shared__ int nsh[RPB][NK];
  __shared__ float zb[RPB][NS][4];
  __shared__ int ib[RPB][NS][4];

  const int wave = threadIdx.x >> 6;
  const int k = threadIdx.x & 63;
  const int b = blockIdx.x * RPB + wave;
  const int center = ids[b];
  char* sb = sbuf[wave];

  if (k < NF / 4)
    ((float4*)fc[wave])[k] = ((const float4*)(features + (size_t)center * NF))[k];
  nsh[wave][k] = adj[(size_t)center * NK + k];
  asm volatile("s_waitcnt lgkmcnt(0)" ::: "memory");  // fc/nsh visible in-wave

  // --- per-lane stage pointers: instr i stages rows i*16..i*16+15, 4 lanes
  // per row (slot = k&3, 64 B of the row's current chunk). Source slot is
  // XOR-swizzled by the row's spread key S(r) = (r>>1)&3 == (k>>3)&3 here.
  const int kq = k >> 2;                       // row sub-index within instr
  const int esrc = (k & 3) ^ ((k >> 3) & 3);   // swizzled source slot
  const float4* f4 = (const float4*)features;
  const float4* g0 = f4 + (size_t)nsh[wave][0 * 16 + kq] * (NF / 4) + esrc;
  const float4* g1 = f4 + (size_t)nsh[wave][1 * 16 + kq] * (NF / 4) + esrc;
  const float4* g2 = f4 + (size_t)nsh[wave][2 * 16 + kq] * (NF / 4) + esrc;
  const float4* g3 = f4 + (size_t)nsh[wave][3 * 16 + kq] * (NF / 4) + esrc;

#define STAGE(half)                                                         \
  do {                                                                      \
    __builtin_amdgcn_global_load_lds((const AS1 void*)g0,                   \
        (AS3 void*)(sb + (half)), 16, 0, 0);                                \
    __builtin_amdgcn_global_load_lds((const AS1 void*)g1,                   \
        (AS3 void*)(sb + (half) + 1024), 16, 0, 0);                         \
    __builtin_amdgcn_global_load_lds((const AS1 void*)g2,                   \
        (AS3 void*)(sb + (half) + 2048), 16, 0, 0);                         \
    __builtin_amdgcn_global_load_lds((const AS1 void*)g3,                   \
        (AS3 void*)(sb + (half) + 3072), 16, 0, 0);                         \
    g0 += 4; g1 += 4; g2 += 4; g3 += 4;                                     \
  } while (0)

  // consume chunk cc: lane k reads its own row (r = k) from LDS; global
  // slot t at LDS offset (t ^ S(k))*16, S(k) = (k>>1)&3. Ascending t ->
  // ascending global element order (bit-exact chain preserved).
  const int S4 = ((k >> 1) & 3) << 4;
  const float4* fc4 = (const float4*)fc[wave];
  float acc = 0.0f;
#define CONSUME(cc, half)                                                   \
  do {                                                                      \
    const char* rb = sb + (half) + k * 64;                                  \
    _Pragma("unroll")                                                       \
    for (int t = 0; t < 4; ++t) {                                           \
      const float4 v = *(const float4*)(rb + ((t << 4) ^ S4));              \
      const float4 f = fc4[(cc) * 4 + t];                                   \
      float d0 = f.x - v.x; acc = acc + d0 * d0;                            \
      float d1 = f.y - v.y; acc = acc + d1 * d1;                            \
      float d2 = f.z - v.z; acc = acc + d2 * d2;                            \
      float d3 = f.w - v.w; acc = acc + d3 * d3;                            \
    }                                                                       \
  } while (0)

  STAGE(0);                                  // chunk 0 -> half 0
#pragma unroll 1
  for (int c = 0; c < 7; ++c) {
    STAGE(((c + 1) & 1) << 12);              // chunk c+1 -> other half
    asm volatile("s_waitcnt vmcnt(4)" ::: "memory");   // chunk c landed
    CONSUME(c, (c & 1) << 12);
    asm volatile("s_waitcnt lgkmcnt(0)" ::: "memory"); // reads done pre-overwrite
  }
  asm volatile("s_waitcnt vmcnt(0)" ::: "memory");
  CONSUME(7, 4096);

  const float ev = xla_exp_f32(-sqrtf(acc));
  esh[wave][k] = ev;
  asm volatile("s_waitcnt lgkmcnt(0)" ::: "memory");

  // sequential 64-term sum (XLA order): all lanes redundantly via float4
  // broadcast reads; identical ascending order -> bit-exact (R6/R8-verified)
  float s = 0.0f;
  const float4* e4 = (const float4*)esh[wave];
#pragma unroll
  for (int i = 0; i < NK / 4; ++i) {
    float4 v = e4[i];
    s = s + v.x; s = s + v.y; s = s + v.z; s = s + v.w;
  }
  const float logit = xla_log_f32(ev / s);

  // gumbel noise shape (16, 16384, 64): flat m = ss*NB*NK + b*NK + k
  // zsh aliases the (dead) stage buffer: 16 x 65 floats = 4160 B < 8192 B
  float (*zsh)[NK + 1] = (float (*)[NK + 1])(void*)sb;
#pragma unroll
  for (int ss = 0; ss < NS; ++ss) {
    uint32_t m = (uint32_t)((ss * NB + b) * NK + k);
    zsh[ss][k] = gumbel_from_bits(jax_random_bits32(m)) + logit;
  }
  asm volatile("s_waitcnt lgkmcnt(0)" ::: "memory");

  // parallel argmax (R6/R8-verified): lane l owns (samp = l>>2, quarter l&3)
  const int samp = k >> 2;
  const int sub = k & 3;
  const int kbase = sub * 16;
  float best = zsh[samp][kbase];
  int bi = kbase;
#pragma unroll 1
  for (int j = 1; j < 16; ++j) {
    const float v = zsh[samp][kbase + j];
    if (v > best) { best = v; bi = kbase + j; }   // strict > : first index
  }
  zb[wave][samp][sub] = best;
  ib[wave][samp][sub] = bi;
  asm volatile("s_waitcnt lgkmcnt(0)" ::: "memory");

  // combine 4 quarters; ascending q + strict > keeps lowest kk on ties
  if (sub == 0) {
    float bb = zb[wave][samp][0];
    int bbi = ib[wave][samp][0];
#pragma unroll
    for (int qq = 1; qq < 4; ++qq) {
      const float v = zb[wave][samp][qq];
      if (v > bb) { bb = v; bbi = ib[wave][samp][qq]; }
    }
    out[b * NS + samp] = nsh[wave][bbi];
  }
#undef STAGE
#undef CONSUME
}

extern "C" void kernel_launch(void* const* d_in, const int* in_sizes, int n_in,
                              void* d_out, int out_size, void* d_ws, size_t ws_size,
                              hipStream_t stream) {
  // inputs: ids(int32)[16384], num_samples(1), features(f32)[100000*128],
  //         batch_size(1), adj_info(int32)[100000*64]
  const int* ids = (const int*)d_in[0];
  const float* features = (const float*)d_in[2];
  const int* adj = (const int*)d_in[4];
  int* out = (int*)d_out;
  (void)in_sizes; (void)n_in; (void)out_size; (void)d_ws; (void)ws_size;

  dns_kernel<<<dim3(NB / RPB), dim3(64 * RPB), 0, stream>>>(ids, features, adj, out);
}

// Round 10
// 81.951 us; speedup vs baseline: 1.2661x; 1.2661x over previous
//
#include <hip/hip_runtime.h>
#include <stdint.h>

#define NB 16384      // batch
#define NK 64         // neighbors per node
#define NF 128        // feature dim
#define NS 16         // samples per row
#define RPB 4         // rows (waves) per block

// ---------------------------------------------------------------------------
// Bit-exact replicas of XLA:CPU's float32 exp/log (Cephes-derived polynomials
// from llvm_ir_runtime.cc GenerateVF32Exp/GenerateVF32Log; fmuladd -> FMA).
// DO NOT TOUCH: verified absmax == 0 vs JAX reference in R1/R4/R6/R7/R8/R9.
// ---------------------------------------------------------------------------
__device__ __forceinline__ float xla_exp_f32(float x_in) {
#pragma clang fp contract(off)
  const float exp_hi = 88.3762626647950f;
  const float exp_lo = -88.3762626647949f;
  const float log2ef = 1.44269504088896341f;
  const float c1 = 0.693359375f;
  const float c2 = -2.12194440e-4f;
  const float p0 = 1.9875691500E-4f;
  const float p1 = 1.3981999507E-3f;
  const float p2 = 8.3334519073E-3f;
  const float p3 = 4.1665795894E-2f;
  const float p4 = 1.6666665459E-1f;
  const float p5 = 5.0000001201E-1f;

  float x = fminf(fmaxf(x_in, exp_lo), exp_hi);
  float fx = floorf(fmaf(x, log2ef, 0.5f));
  float tmp = c1 * fx;
  float z2 = c2 * fx;
  x = x - tmp;
  x = x - z2;
  float z = x * x;
  float y = fmaf(x, p0, p1);
  y = fmaf(y, x, p2);
  y = fmaf(y, x, p3);
  y = fmaf(y, x, p4);
  y = fmaf(y, x, p5);
  y = fmaf(y, z, x);
  y = y + 1.0f;
  int n = (int)fx;
  float two_n = __int_as_float((n + 127) << 23);
  return fmaxf(y * two_n, x_in);
}

__device__ __forceinline__ float xla_log_f32(float x_in) {
#pragma clang fp contract(off)
  const float sqrthf = 0.707106781186547524f;
  const float p0 = 7.0376836292E-2f;
  const float p1 = -1.1514610310E-1f;
  const float p2 = 1.1676998740E-1f;
  const float p3 = -1.2420140846E-1f;
  const float p4 = 1.4249322787E-1f;
  const float p5 = -1.6668057665E-1f;
  const float p6 = 2.0000714765E-1f;
  const float p7 = -2.4999993993E-1f;
  const float p8 = 3.3333331174E-1f;
  const float q1 = -2.12194440e-4f;
  const float q2 = 0.693359375f;

  float t = fmaxf(x_in, __uint_as_float(0x00800000u));
  uint32_t bits = __float_as_uint(t);
  float e = (float)((int)(bits >> 23) - 0x7f) + 1.0f;
  float m = __uint_as_float((bits & 0x007fffffu) | 0x3f000000u);
  bool lt = (m < sqrthf);
  float madd = lt ? m : 0.0f;
  e = e - (lt ? 1.0f : 0.0f);
  m = (m + madd) - 1.0f;

  float z = m * m;
  float y = fmaf(m, p0, p1);
  y = fmaf(y, m, p2);
  y = fmaf(y, m, p3);
  y = fmaf(y, m, p4);
  y = fmaf(y, m, p5);
  y = fmaf(y, m, p6);
  y = fmaf(y, m, p7);
  y = fmaf(y, m, p8);
  y = y * m;
  y = y * z;
  y = fmaf(e, q1, y);
  y = y - 0.5f * z;
  float r = m + y;
  r = fmaf(e, q2, r);
  return r;
}

// ---------------------------------------------------------------------------
// Threefry-2x32 with key (0, 42) == jax.random.key(42).
// ---------------------------------------------------------------------------
__device__ __forceinline__ void threefry2x32_k42(uint32_t c0, uint32_t c1,
                                                 uint32_t& o0, uint32_t& o1) {
  const uint32_t k0 = 0u, k1 = 42u;
  const uint32_t k2 = k0 ^ k1 ^ 0x1BD11BDAu;
  uint32_t x0 = c0 + k0, x1 = c1 + k1;
#define TF_R(r) { x0 += x1; x1 = (x1 << (r)) | (x1 >> (32 - (r))); x1 ^= x0; }
  TF_R(13) TF_R(15) TF_R(26) TF_R(6)
  x0 += k1; x1 += k2 + 1u;
  TF_R(17) TF_R(29) TF_R(16) TF_R(24)
  x0 += k2; x1 += k0 + 2u;
  TF_R(13) TF_R(15) TF_R(26) TF_R(6)
  x0 += k0; x1 += k1 + 3u;
  TF_R(17) TF_R(29) TF_R(16) TF_R(24)
  x0 += k1; x1 += k2 + 4u;
  TF_R(13) TF_R(15) TF_R(26) TF_R(6)
  x0 += k2; x1 += k0 + 5u;
#undef TF_R
  o0 = x0; o1 = x1;
}

// jax partitionable threefry, 32-bit path: bits[m] = out0 ^ out1, m < 2^24.
__device__ __forceinline__ uint32_t jax_random_bits32(uint32_t m) {
  uint32_t a, b;
  threefry2x32_k42(0u, m, a, b);
  return a ^ b;
}

__device__ __forceinline__ float gumbel_from_bits(uint32_t bits) {
#pragma clang fp contract(off)
  const float tiny = 1.17549435e-38f;
  float f = __uint_as_float((bits >> 9) | 0x3f800000u) - 1.0f;
  float u = fmaxf(tiny, f + tiny);
  return -xla_log_f32(-xla_log_f32(u));
}

#define AS1 __attribute__((address_space(1)))
#define AS3 __attribute__((address_space(3)))

// ---------------------------------------------------------------------------
// R8 gather structure VERBATIM (proven 91.8 us) + gumbel precompute moved
// into the 4 vmcnt(0) drain shadows. Per quarter: STAGE 8 full-line loads ->
// compute 4 logit-independent gumbels (~500 VALU ops, covers HBM latency) ->
// vmcnt(0) -> consume. Quarter loop fully unrolled so pg[] is statically
// indexed (no scratch). Math blocks verbatim (absmax-0 chain preserved).
// ---------------------------------------------------------------------------
__global__ void __launch_bounds__(256)
dns_kernel(const int* __restrict__ ids, const float* __restrict__ features,
           const int* __restrict__ adj, int* __restrict__ out) {
#pragma clang fp contract(off)
  __shared__ __align__(16) char sbuf[RPB][8192];   // stage buf, later zsh
  __shared__ __align__(16) float fc[RPB][NF];
  __shared__ __align__(16) float esh[RPB][NK];
  __shared__ int nsh[RPB][NK];
  __shared__ float zb[RPB][NS][4];
  __shared__ int ib[RPB][NS][4];

  const int wave = threadIdx.x >> 6;
  const int k = threadIdx.x & 63;
  const int b = blockIdx.x * RPB + wave;
  const int center = ids[b];
  char* sb = sbuf[wave];

  if (k < NF / 4)
    ((float4*)fc[wave])[k] = ((const float4*)(features + (size_t)center * NF))[k];
  nsh[wave][k] = adj[(size_t)center * NK + k];
  asm volatile("s_waitcnt lgkmcnt(0)" ::: "memory");  // fc/nsh visible in-wave

  const int rg = k >> 3;   // row sub-index within a stage instruction
  const int eg = k & 7;    // element slot within the 128 B quarter

  // STAGE quarter q (R8 verbatim): instr i stages rows i*8..i*8+7, one full
  // 128 B line per row, 8 lanes per line; source slot XOR-swizzled (m173).
#define STAGEQ(q)                                                            \
  do {                                                                       \
    _Pragma("unroll")                                                        \
    for (int i = 0; i < 8; ++i) {                                            \
      const int r = i * 8 + rg;                                              \
      const int rn = nsh[wave][r];                                           \
      const int es = eg ^ (r & 7);                                           \
      const float4* g =                                                      \
          (const float4*)features + ((size_t)rn * (NF / 4) + (q) * 8 + es);  \
      __builtin_amdgcn_global_load_lds((const AS1 void*)g,                   \
          (AS3 void*)(sb + i * 1024), 16, 0, 0);                             \
    }                                                                        \
  } while (0)

  // gumbels for samples (q)*4 .. (q)*4+3 -- logit-independent VALU work,
  // fills the HBM latency between STAGE issue and the vmcnt(0) drain.
  // flat m = ss*NB*NK + b*NK + k  (noise shape (16,16384,64))
#define GUMQ(q)                                                              \
  do {                                                                       \
    _Pragma("unroll")                                                        \
    for (int i2 = 0; i2 < 4; ++i2) {                                         \
      const int ss = (q) * 4 + i2;                                           \
      const uint32_t m = (uint32_t)((ss * NB + b) * NK + k);                 \
      pg[ss] = gumbel_from_bits(jax_random_bits32(m));                       \
    }                                                                        \
  } while (0)

  // consume quarter q (R8 verbatim): lane k reads its own row, elements in
  // ascending global order j = q*8+j2 -> bit-exact sequential chain.
#define CONSUMEQ(q)                                                          \
  do {                                                                       \
    _Pragma("unroll")                                                        \
    for (int j2 = 0; j2 < 8; ++j2) {                                         \
      const float4 v =                                                       \
          *(const float4*)(sb + k * 128 + ((j2 ^ (k & 7)) << 4));            \
      const int j = (q) * 8 + j2;                                            \
      float d0 = fc[wave][4 * j + 0] - v.x; acc = acc + d0 * d0;             \
      float d1 = fc[wave][4 * j + 1] - v.y; acc = acc + d1 * d1;             \
      float d2 = fc[wave][4 * j + 2] - v.z; acc = acc + d2 * d2;             \
      float d3 = fc[wave][4 * j + 3] - v.w; acc = acc + d3 * d3;             \
    }                                                                        \
  } while (0)

  float pg[16];
  float acc = 0.0f;

  STAGEQ(0); GUMQ(0);
  asm volatile("s_waitcnt vmcnt(0)" ::: "memory");
  CONSUMEQ(0);
  asm volatile("s_waitcnt lgkmcnt(0)" ::: "memory");

  STAGEQ(1); GUMQ(1);
  asm volatile("s_waitcnt vmcnt(0)" ::: "memory");
  CONSUMEQ(1);
  asm volatile("s_waitcnt lgkmcnt(0)" ::: "memory");

  STAGEQ(2); GUMQ(2);
  asm volatile("s_waitcnt vmcnt(0)" ::: "memory");
  CONSUMEQ(2);
  asm volatile("s_waitcnt lgkmcnt(0)" ::: "memory");

  STAGEQ(3); GUMQ(3);
  asm volatile("s_waitcnt vmcnt(0)" ::: "memory");
  CONSUMEQ(3);
  asm volatile("s_waitcnt lgkmcnt(0)" ::: "memory");

  const float ev = xla_exp_f32(-sqrtf(acc));
  esh[wave][k] = ev;
  asm volatile("s_waitcnt lgkmcnt(0)" ::: "memory");

  // sequential 64-term sum (XLA order): all lanes redundantly via float4
  // broadcast reads; identical ascending order -> bit-exact (R6/R8-verified)
  float s = 0.0f;
  const float4* e4 = (const float4*)esh[wave];
#pragma unroll
  for (int i = 0; i < NK / 4; ++i) {
    float4 v = e4[i];
    s = s + v.x; s = s + v.y; s = s + v.z; s = s + v.w;
  }
  const float logit = xla_log_f32(ev / s);

  // zsh aliases the (dead) stage buffer: 16 x 65 floats = 4160 B < 8192 B
  float (*zsh)[NK + 1] = (float (*)[NK + 1])(void*)sb;
#pragma unroll
  for (int ss = 0; ss < NS; ++ss) {
    zsh[ss][k] = pg[ss] + logit;
  }
  asm volatile("s_waitcnt lgkmcnt(0)" ::: "memory");

  // parallel argmax (R6/R8-verified): lane l owns (samp = l>>2, quarter l&3)
  const int samp = k >> 2;
  const int sub = k & 3;
  const int kbase = sub * 16;
  float best = zsh[samp][kbase];
  int bi = kbase;
#pragma unroll 1
  for (int j = 1; j < 16; ++j) {
    const float v = zsh[samp][kbase + j];
    if (v > best) { best = v; bi = kbase + j; }   // strict > : first index
  }
  zb[wave][samp][sub] = best;
  ib[wave][samp][sub] = bi;
  asm volatile("s_waitcnt lgkmcnt(0)" ::: "memory");

  // combine 4 quarters; ascending q + strict > keeps lowest kk on ties
  if (sub == 0) {
    float bb = zb[wave][samp][0];
    int bbi = ib[wave][samp][0];
#pragma unroll
    for (int qq = 1; qq < 4; ++qq) {
      const float v = zb[wave][samp][qq];
      if (v > bb) { bb = v; bbi = ib[wave][samp][qq]; }
    }
    out[b * NS + samp] = nsh[wave][bbi];
  }
#undef STAGEQ
#undef GUMQ
#undef CONSUMEQ
}

extern "C" void kernel_launch(void* const* d_in, const int* in_sizes, int n_in,
                              void* d_out, int out_size, void* d_ws, size_t ws_size,
                              hipStream_t stream) {
  // inputs: ids(int32)[16384], num_samples(1), features(f32)[100000*128],
  //         batch_size(1), adj_info(int32)[100000*64]
  const int* ids = (const int*)d_in[0];
  const float* features = (const float*)d_in[2];
  const int* adj = (const int*)d_in[4];
  int* out = (int*)d_out;
  (void)in_sizes; (void)n_in; (void)out_size; (void)d_ws; (void)ws_size;

  dns_kernel<<<dim3(NB / RPB), dim3(64 * RPB), 0, stream>>>(ids, features, adj, out);
}

// Round 11
// 81.614 us; speedup vs baseline: 1.2713x; 1.0041x over previous
//
#include <hip/hip_runtime.h>
#include <stdint.h>

#define NB 16384      // batch
#define NK 64         // neighbors per node
#define NF 128        // feature dim
#define NS 16         // samples per row
#define RPB 4         // rows (waves) per block

// ---------------------------------------------------------------------------
// Bit-exact replicas of XLA:CPU's float32 exp/log (Cephes-derived polynomials
// from llvm_ir_runtime.cc GenerateVF32Exp/GenerateVF32Log; fmuladd -> FMA).
// DO NOT TOUCH: verified absmax == 0 vs JAX reference in R1/R4/R6-R10.
// ---------------------------------------------------------------------------
__device__ __forceinline__ float xla_exp_f32(float x_in) {
#pragma clang fp contract(off)
  const float exp_hi = 88.3762626647950f;
  const float exp_lo = -88.3762626647949f;
  const float log2ef = 1.44269504088896341f;
  const float c1 = 0.693359375f;
  const float c2 = -2.12194440e-4f;
  const float p0 = 1.9875691500E-4f;
  const float p1 = 1.3981999507E-3f;
  const float p2 = 8.3334519073E-3f;
  const float p3 = 4.1665795894E-2f;
  const float p4 = 1.6666665459E-1f;
  const float p5 = 5.0000001201E-1f;

  float x = fminf(fmaxf(x_in, exp_lo), exp_hi);
  float fx = floorf(fmaf(x, log2ef, 0.5f));
  float tmp = c1 * fx;
  float z2 = c2 * fx;
  x = x - tmp;
  x = x - z2;
  float z = x * x;
  float y = fmaf(x, p0, p1);
  y = fmaf(y, x, p2);
  y = fmaf(y, x, p3);
  y = fmaf(y, x, p4);
  y = fmaf(y, x, p5);
  y = fmaf(y, z, x);
  y = y + 1.0f;
  int n = (int)fx;
  float two_n = __int_as_float((n + 127) << 23);
  return fmaxf(y * two_n, x_in);
}

__device__ __forceinline__ float xla_log_f32(float x_in) {
#pragma clang fp contract(off)
  const float sqrthf = 0.707106781186547524f;
  const float p0 = 7.0376836292E-2f;
  const float p1 = -1.1514610310E-1f;
  const float p2 = 1.1676998740E-1f;
  const float p3 = -1.2420140846E-1f;
  const float p4 = 1.4249322787E-1f;
  const float p5 = -1.6668057665E-1f;
  const float p6 = 2.0000714765E-1f;
  const float p7 = -2.4999993993E-1f;
  const float p8 = 3.3333331174E-1f;
  const float q1 = -2.12194440e-4f;
  const float q2 = 0.693359375f;

  float t = fmaxf(x_in, __uint_as_float(0x00800000u));
  uint32_t bits = __float_as_uint(t);
  float e = (float)((int)(bits >> 23) - 0x7f) + 1.0f;
  float m = __uint_as_float((bits & 0x007fffffu) | 0x3f000000u);
  bool lt = (m < sqrthf);
  float madd = lt ? m : 0.0f;
  e = e - (lt ? 1.0f : 0.0f);
  m = (m + madd) - 1.0f;

  float z = m * m;
  float y = fmaf(m, p0, p1);
  y = fmaf(y, m, p2);
  y = fmaf(y, m, p3);
  y = fmaf(y, m, p4);
  y = fmaf(y, m, p5);
  y = fmaf(y, m, p6);
  y = fmaf(y, m, p7);
  y = fmaf(y, m, p8);
  y = y * m;
  y = y * z;
  y = fmaf(e, q1, y);
  y = y - 0.5f * z;
  float r = m + y;
  r = fmaf(e, q2, r);
  return r;
}

// ---------------------------------------------------------------------------
// Threefry-2x32 with key (0, 42) == jax.random.key(42).
// ---------------------------------------------------------------------------
__device__ __forceinline__ void threefry2x32_k42(uint32_t c0, uint32_t c1,
                                                 uint32_t& o0, uint32_t& o1) {
  const uint32_t k0 = 0u, k1 = 42u;
  const uint32_t k2 = k0 ^ k1 ^ 0x1BD11BDAu;
  uint32_t x0 = c0 + k0, x1 = c1 + k1;
#define TF_R(r) { x0 += x1; x1 = (x1 << (r)) | (x1 >> (32 - (r))); x1 ^= x0; }
  TF_R(13) TF_R(15) TF_R(26) TF_R(6)
  x0 += k1; x1 += k2 + 1u;
  TF_R(17) TF_R(29) TF_R(16) TF_R(24)
  x0 += k2; x1 += k0 + 2u;
  TF_R(13) TF_R(15) TF_R(26) TF_R(6)
  x0 += k0; x1 += k1 + 3u;
  TF_R(17) TF_R(29) TF_R(16) TF_R(24)
  x0 += k1; x1 += k2 + 4u;
  TF_R(13) TF_R(15) TF_R(26) TF_R(6)
  x0 += k2; x1 += k0 + 5u;
#undef TF_R
  o0 = x0; o1 = x1;
}

// jax partitionable threefry, 32-bit path: bits[m] = out0 ^ out1, m < 2^24.
__device__ __forceinline__ uint32_t jax_random_bits32(uint32_t m) {
  uint32_t a, b;
  threefry2x32_k42(0u, m, a, b);
  return a ^ b;
}

__device__ __forceinline__ float gumbel_from_bits(uint32_t bits) {
#pragma clang fp contract(off)
  const float tiny = 1.17549435e-38f;
  float f = __uint_as_float((bits >> 9) | 0x3f800000u) - 1.0f;
  float u = fmaxf(tiny, f + tiny);
  return -xla_log_f32(-xla_log_f32(u));
}

#define AS1 __attribute__((address_space(1)))
#define AS3 __attribute__((address_space(3)))

// ---------------------------------------------------------------------------
// R10 structure + two overhead cuts:
//  (1) stage pointers gp0..gp7 computed ONCE (note (i*8+rg)&7 == rg, so the
//      swizzle slot es = eg^rg is uniform across stage instrs); quarters
//      advance by pointer bump +8 float4 (R9-proven addressing).
//  (2) gumbels redistributed: 6 cover the ids->adj/fc prologue latency,
//      3/3/2/2 cover the four vmcnt(0) drain shadows.
// All math blocks verbatim (absmax-0 chain preserved).
// ---------------------------------------------------------------------------
__global__ void __launch_bounds__(256)
dns_kernel(const int* __restrict__ ids, const float* __restrict__ features,
           const int* __restrict__ adj, int* __restrict__ out) {
#pragma clang fp contract(off)
  __shared__ __align__(16) char sbuf[RPB][8192];   // stage buf, later zsh
  __shared__ __align__(16) float fc[RPB][NF];
  __shared__ __align__(16) float esh[RPB][NK];
  __shared__ int nsh[RPB][NK];
  __shared__ float zb[RPB][NS][4];
  __shared__ int ib[RPB][NS][4];

  const int wave = threadIdx.x >> 6;
  const int k = threadIdx.x & 63;
  const int b = blockIdx.x * RPB + wave;
  char* sb = sbuf[wave];

  float pg[16];
  // gumbel flat index m = ss*NB*NK + b*NK + k  (noise shape (16,16384,64));
  // pure VALU, independent of every load -> scheduler fills load latency.
#define GUM1(ss) pg[ss] = gumbel_from_bits(                                  \
      jax_random_bits32((uint32_t)(((ss) * NB + b) * NK + k)))

  const int center = ids[b];
  GUM1(0); GUM1(1); GUM1(2);                    // cover ids-load latency

  if (k < NF / 4)
    ((float4*)fc[wave])[k] = ((const float4*)(features + (size_t)center * NF))[k];
  nsh[wave][k] = adj[(size_t)center * NK + k];

  GUM1(3); GUM1(4); GUM1(5);                    // cover adj/fc-load latency
  asm volatile("s_waitcnt lgkmcnt(0)" ::: "memory");  // fc/nsh visible in-wave

  const int rg = k >> 3;   // row sub-index within a stage instruction
  const int eg = k & 7;    // element slot within the 128 B quarter
  const int es = eg ^ rg;  // swizzled source slot (uniform across instrs)

  // stage base pointers, one per stage-instruction slot (computed once)
  const float4* f4b = (const float4*)features;
#define MKGP(i) const float4* gp##i = f4b + (size_t)nsh[wave][(i) * 8 + rg] * (NF / 4) + es
  MKGP(0); MKGP(1); MKGP(2); MKGP(3); MKGP(4); MKGP(5); MKGP(6); MKGP(7);
#undef MKGP

  // STAGE one quarter: 8 instrs, each stages rows i*8..i*8+7 (one full 128 B
  // line per row, 8 lanes per line); then bump pointers to the next quarter.
#define STAGEQ()                                                             \
  do {                                                                       \
    __builtin_amdgcn_global_load_lds((const AS1 void*)gp0,                   \
        (AS3 void*)(sb + 0 * 1024), 16, 0, 0);                               \
    __builtin_amdgcn_global_load_lds((const AS1 void*)gp1,                   \
        (AS3 void*)(sb + 1 * 1024), 16, 0, 0);                               \
    __builtin_amdgcn_global_load_lds((const AS1 void*)gp2,                   \
        (AS3 void*)(sb + 2 * 1024), 16, 0, 0);                               \
    __builtin_amdgcn_global_load_lds((const AS1 void*)gp3,                   \
        (AS3 void*)(sb + 3 * 1024), 16, 0, 0);                               \
    __builtin_amdgcn_global_load_lds((const AS1 void*)gp4,                   \
        (AS3 void*)(sb + 4 * 1024), 16, 0, 0);                               \
    __builtin_amdgcn_global_load_lds((const AS1 void*)gp5,                   \
        (AS3 void*)(sb + 5 * 1024), 16, 0, 0);                               \
    __builtin_amdgcn_global_load_lds((const AS1 void*)gp6,                   \
        (AS3 void*)(sb + 6 * 1024), 16, 0, 0);                               \
    __builtin_amdgcn_global_load_lds((const AS1 void*)gp7,                   \
        (AS3 void*)(sb + 7 * 1024), 16, 0, 0);                               \
    gp0 += 8; gp1 += 8; gp2 += 8; gp3 += 8;                                  \
    gp4 += 8; gp5 += 8; gp6 += 8; gp7 += 8;                                  \
  } while (0)

  // consume quarter q (R8/R10 verbatim): lane k reads its own row, elements
  // in ascending global order j = q*8+j2 -> bit-exact sequential chain.
#define CONSUMEQ(q)                                                          \
  do {                                                                       \
    _Pragma("unroll")                                                        \
    for (int j2 = 0; j2 < 8; ++j2) {                                         \
      const float4 v =                                                       \
          *(const float4*)(sb + k * 128 + ((j2 ^ (k & 7)) << 4));            \
      const int j = (q) * 8 + j2;                                            \
      float d0 = fc[wave][4 * j + 0] - v.x; acc = acc + d0 * d0;             \
      float d1 = fc[wave][4 * j + 1] - v.y; acc = acc + d1 * d1;             \
      float d2 = fc[wave][4 * j + 2] - v.z; acc = acc + d2 * d2;             \
      float d3 = fc[wave][4 * j + 3] - v.w; acc = acc + d3 * d3;             \
    }                                                                        \
  } while (0)

  float acc = 0.0f;

  STAGEQ(); GUM1(6); GUM1(7); GUM1(8);
  asm volatile("s_waitcnt vmcnt(0)" ::: "memory");
  CONSUMEQ(0);
  asm volatile("s_waitcnt lgkmcnt(0)" ::: "memory");

  STAGEQ(); GUM1(9); GUM1(10); GUM1(11);
  asm volatile("s_waitcnt vmcnt(0)" ::: "memory");
  CONSUMEQ(1);
  asm volatile("s_waitcnt lgkmcnt(0)" ::: "memory");

  STAGEQ(); GUM1(12); GUM1(13);
  asm volatile("s_waitcnt vmcnt(0)" ::: "memory");
  CONSUMEQ(2);
  asm volatile("s_waitcnt lgkmcnt(0)" ::: "memory");

  STAGEQ(); GUM1(14); GUM1(15);
  asm volatile("s_waitcnt vmcnt(0)" ::: "memory");
  CONSUMEQ(3);
  asm volatile("s_waitcnt lgkmcnt(0)" ::: "memory");

  const float ev = xla_exp_f32(-sqrtf(acc));
  esh[wave][k] = ev;
  asm volatile("s_waitcnt lgkmcnt(0)" ::: "memory");

  // sequential 64-term sum (XLA order): all lanes redundantly via float4
  // broadcast reads; identical ascending order -> bit-exact (R6/R8-verified)
  float s = 0.0f;
  const float4* e4 = (const float4*)esh[wave];
#pragma unroll
  for (int i = 0; i < NK / 4; ++i) {
    float4 v = e4[i];
    s = s + v.x; s = s + v.y; s = s + v.z; s = s + v.w;
  }
  const float logit = xla_log_f32(ev / s);

  // zsh aliases the (dead) stage buffer: 16 x 65 floats = 4160 B < 8192 B
  float (*zsh)[NK + 1] = (float (*)[NK + 1])(void*)sb;
#pragma unroll
  for (int ss = 0; ss < NS; ++ss) {
    zsh[ss][k] = pg[ss] + logit;
  }
  asm volatile("s_waitcnt lgkmcnt(0)" ::: "memory");

  // parallel argmax (R6/R8-verified): lane l owns (samp = l>>2, quarter l&3)
  const int samp = k >> 2;
  const int sub = k & 3;
  const int kbase = sub * 16;
  float best = zsh[samp][kbase];
  int bi = kbase;
#pragma unroll 1
  for (int j = 1; j < 16; ++j) {
    const float v = zsh[samp][kbase + j];
    if (v > best) { best = v; bi = kbase + j; }   // strict > : first index
  }
  zb[wave][samp][sub] = best;
  ib[wave][samp][sub] = bi;
  asm volatile("s_waitcnt lgkmcnt(0)" ::: "memory");

  // combine 4 quarters; ascending q + strict > keeps lowest kk on ties
  if (sub == 0) {
    float bb = zb[wave][samp][0];
    int bbi = ib[wave][samp][0];
#pragma unroll
    for (int qq = 1; qq < 4; ++qq) {
      const float v = zb[wave][samp][qq];
      if (v > bb) { bb = v; bbi = ib[wave][samp][qq]; }
    }
    out[b * NS + samp] = nsh[wave][bbi];
  }
#undef STAGEQ
#undef CONSUMEQ
#undef GUM1
}

extern "C" void kernel_launch(void* const* d_in, const int* in_sizes, int n_in,
                              void* d_out, int out_size, void* d_ws, size_t ws_size,
                              hipStream_t stream) {
  // inputs: ids(int32)[16384], num_samples(1), features(f32)[100000*128],
  //         batch_size(1), adj_info(int32)[100000*64]
  const int* ids = (const int*)d_in[0];
  const float* features = (const float*)d_in[2];
  const int* adj = (const int*)d_in[4];
  int* out = (int*)d_out;
  (void)in_sizes; (void)n_in; (void)out_size; (void)d_ws; (void)ws_size;

  dns_kernel<<<dim3(NB / RPB), dim3(64 * RPB), 0, stream>>>(ids, features, adj, out);
}